// Round 3
// baseline (272.167 us; speedup 1.0000x reference)
//
#include <hip/hip_runtime.h>
#include <stdint.h>
#include <math.h>

// MultiHeadAttention: B=2, S=2048, D=1024, H=16, DH=64
// R3: attn S^T operand-swap — P stays in registers (QK computes S^T whose C-layout
// IS the 16x16x16 A-layout); PV via mfma_16x16x16bf16_1k; l via ones-MFMA.
// gemm_out retiled 128x64 (512 blocks, 2/CU). Launch merges: mask->cvt3, wqkv+wo.

typedef __attribute__((ext_vector_type(8))) short short8;
typedef __attribute__((ext_vector_type(4))) short short4b;
typedef __attribute__((ext_vector_type(4))) float floatx4;

#define LOG2E 1.44269504088896340736f

__device__ __forceinline__ unsigned short f32_bf16(float f) {
  union { float f; unsigned u; } c; c.f = f;
  return (unsigned short)((c.u + 0x7FFFu + ((c.u >> 16) & 1u)) >> 16);
}
__device__ __forceinline__ float bf16_f32(unsigned short u) {
  union { unsigned u; float f; } c; c.u = ((unsigned)u) << 16;
  return c.f;
}
__device__ __forceinline__ void gld16(const void* g, void* l) {
  __builtin_amdgcn_global_load_lds((const __attribute__((address_space(1))) void*)g,
                                   (__attribute__((address_space(3))) void*)l, 16, 0, 0);
}
// pack 4 fp32 -> 4 bf16 (truncate) into an A-frag for mfma_16x16x16
__device__ __forceinline__ short4b pack_bf16x4(float a0, float a1, float a2, float a3) {
  union { float f; unsigned u; } c0, c1, c2, c3;
  c0.f = a0; c1.f = a1; c2.f = a2; c3.f = a3;
  union { unsigned u[2]; short4b s; } r;
  r.u[0] = __builtin_amdgcn_perm(c1.u, c0.u, 0x07060302u);  // hi=bf16(a1), lo=bf16(a0)
  r.u[1] = __builtin_amdgcn_perm(c3.u, c2.u, 0x07060302u);
  return r.s;
}

// ---------------- pre-passes ----------------

__global__ __launch_bounds__(256) void cvt3_kernel(
    const float* __restrict__ a, const float* __restrict__ b, const float* __restrict__ c,
    unsigned short* __restrict__ oa, unsigned short* __restrict__ ob, unsigned short* __restrict__ oc,
    const int* __restrict__ mask, float* __restrict__ mb, int n4) {
  int i = blockIdx.x * 256 + threadIdx.x;
  if (blockIdx.y == 0 && blockIdx.x < 16) {  // fused mask bias (4096 elems)
    int j = blockIdx.x * 256 + threadIdx.x;
    mb[j] = (mask[j] == 0) ? (-1.0e9f * LOG2E) : 0.0f;
  }
  if (i >= n4) return;
  const float* in; unsigned short* out;
  if (blockIdx.y == 0) { in = a; out = oa; }
  else if (blockIdx.y == 1) { in = b; out = ob; }
  else { in = c; out = oc; }
  float4 v = reinterpret_cast<const float4*>(in)[i];
  ushort4 o;
  o.x = f32_bf16(v.x); o.y = f32_bf16(v.y); o.z = f32_bf16(v.z); o.w = f32_bf16(v.w);
  reinterpret_cast<ushort4*>(out)[i] = o;
}

// merged weight transposes: z<48 -> per-head qkv [16][1024][64]; z==48 -> Wo [1024][1024]
__global__ __launch_bounds__(256) void transpose_w_kernel(
    const float* __restrict__ w0, const float* __restrict__ w1, const float* __restrict__ w2,
    const float* __restrict__ wo,
    unsigned short* __restrict__ o0, unsigned short* __restrict__ o1, unsigned short* __restrict__ o2,
    unsigned short* __restrict__ oo) {
  __shared__ float t[32][33];
  const int tx = threadIdx.x & 31, ty = threadIdx.x >> 5;
  const int zb = blockIdx.z;
  const float* in; unsigned short* out; int R, C, z, r0, c0;
  if (zb < 48) {
    if (blockIdx.y >= 2) return;
    const int sel = zb >> 4; z = zb & 15;
    in = (sel == 0) ? w0 : (sel == 1) ? w1 : w2;
    out = (sel == 0) ? o0 : (sel == 1) ? o1 : o2;
    R = 1024; C = 64;
  } else {
    in = wo; out = oo; R = 1024; C = 1024; z = 0;
  }
  r0 = blockIdx.x * 32; c0 = blockIdx.y * 32;
  const float* inp = in + (size_t)z * R * C;
  #pragma unroll
  for (int j = 0; j < 4; ++j)
    t[ty + j * 8][tx] = inp[(size_t)(r0 + ty + j * 8) * C + c0 + tx];
  __syncthreads();
  #pragma unroll
  for (int j = 0; j < 4; ++j)
    out[((size_t)z * C + c0 + ty + j * 8) * R + r0 + tx] = f32_bf16(t[tx][ty + j * 8]);
}

// bf16 [z][R][C] -> bf16 out[(z*C + c)*R + r]
__global__ __launch_bounds__(256) void transpose_v_kernel(
    const unsigned short* __restrict__ in, unsigned short* __restrict__ out, int R, int C) {
  __shared__ unsigned short t[32][33];
  const int z = blockIdx.z;
  const unsigned short* inp = in + (size_t)z * R * C;
  const int r0 = blockIdx.x * 32, c0 = blockIdx.y * 32;
  const int tx = threadIdx.x & 31, ty = threadIdx.x >> 5;
  #pragma unroll
  for (int j = 0; j < 4; ++j)
    t[ty + j * 8][tx] = inp[(size_t)(r0 + ty + j * 8) * C + c0 + tx];
  __syncthreads();
  #pragma unroll
  for (int j = 0; j < 4; ++j)
    out[((size_t)z * C + c0 + ty + j * 8) * R + r0 + tx] = t[tx][ty + j * 8];
}

// ---------------- GEMM core 128x128 (m97 structure) ----------------

__device__ __forceinline__ void gemm_core(
    const unsigned short* __restrict__ A, const unsigned short* __restrict__ Bt,
    int K, int blockM, int blockN,
    unsigned short* As, unsigned short* Bs, floatx4 acc[4][4]) {
  const int tid = threadIdx.x;
  const int w = tid >> 6;
  const int lane = tid & 63;
  const int quad = lane >> 4, l15 = lane & 15;
  const int wm = w & 1, wn = w >> 1;
  const int srow = lane >> 2;
  const int scol = (lane & 3) * 8;

  #pragma unroll
  for (int mi = 0; mi < 4; ++mi)
    #pragma unroll
    for (int ni = 0; ni < 4; ++ni)
      acc[mi][ni] = (floatx4){0.f, 0.f, 0.f, 0.f};

  const unsigned short* Arow = A + (size_t)blockM * K;
  const unsigned short* Brow = Bt + (size_t)blockN * K;

  for (int k0 = 0; k0 < K; k0 += 32) {
    #pragma unroll
    for (int i = 0; i < 2; ++i) {
      int row = w * 32 + i * 16;
      gld16(Arow + (size_t)(row + srow) * K + k0 + scol, As + row * 32);
      gld16(Brow + (size_t)(row + srow) * K + k0 + scol, Bs + row * 32);
    }
    __syncthreads();
    short8 bf[4];
    #pragma unroll
    for (int ni = 0; ni < 4; ++ni)
      bf[ni] = *(const short8*)(Bs + (wn * 64 + ni * 16 + l15) * 32 + quad * 8);
    #pragma unroll
    for (int mi = 0; mi < 4; ++mi) {
      short8 af = *(const short8*)(As + (wm * 64 + mi * 16 + l15) * 32 + quad * 8);
      #pragma unroll
      for (int ni = 0; ni < 4; ++ni)
        acc[mi][ni] = __builtin_amdgcn_mfma_f32_16x16x32_bf16(af, bf[ni], acc[mi][ni], 0, 0, 0);
    }
    __syncthreads();
  }
}

struct ProjArgs {
  const unsigned short* A[3];
  const unsigned short* Bt[3];
  const float* bias[3];
  unsigned short* out[3];
};

__global__ __launch_bounds__(256) void gemm_proj_kernel(ProjArgs pa, int K) {
  __shared__ unsigned short As[128 * 32];
  __shared__ unsigned short Bs[128 * 32];
  const int z = blockIdx.z;
  const int blockN = blockIdx.x * 128, blockM = blockIdx.y * 128;
  floatx4 acc[4][4];
  gemm_core(pa.A[z], pa.Bt[z], K, blockM, blockN, As, Bs, acc);

  const float* bias = pa.bias[z];
  unsigned short* outp = pa.out[z];
  const int tid = threadIdx.x, w = tid >> 6, lane = tid & 63;
  const int quad = lane >> 4, l15 = lane & 15;
  const int wm = w & 1, wn = w >> 1;
  #pragma unroll
  for (int mi = 0; mi < 4; ++mi)
    #pragma unroll
    for (int ni = 0; ni < 4; ++ni) {
      const int n = blockN + wn * 64 + ni * 16 + l15;
      const int h = n >> 6, e = n & 63;
      const float bv = bias[n];
      #pragma unroll
      for (int r = 0; r < 4; ++r) {
        const int m = blockM + wm * 64 + mi * 16 + quad * 4 + r;
        const int b = m >> 11, s = m & 2047;
        outp[(((size_t)b * 16 + h) * 2048 + s) * 64 + e] = f32_bf16(acc[mi][ni][r] + bv);
      }
    }
}

// output projection, tile 128M x 64N -> 512 blocks (2/CU)
__global__ __launch_bounds__(256) void gemm_out_kernel(
    const unsigned short* __restrict__ A, const unsigned short* __restrict__ Bt,
    const float* __restrict__ bias, float* __restrict__ out, int K, int N) {
  __shared__ unsigned short As[128 * 32];
  __shared__ unsigned short Bs[64 * 32];
  const int tid = threadIdx.x;
  const int w = tid >> 6, lane = tid & 63;
  const int quad = lane >> 4, l15 = lane & 15;
  const int wm = w & 1, wn = w >> 1;
  const int srow = lane >> 2;
  const int scol = (lane & 3) * 8;
  const int blockN = blockIdx.x * 64, blockM = blockIdx.y * 128;

  floatx4 acc[4][2];
  #pragma unroll
  for (int mi = 0; mi < 4; ++mi)
    #pragma unroll
    for (int ni = 0; ni < 2; ++ni)
      acc[mi][ni] = (floatx4){0.f, 0.f, 0.f, 0.f};

  const unsigned short* Arow = A + (size_t)blockM * K;
  const unsigned short* Brow = Bt + (size_t)blockN * K;

  for (int k0 = 0; k0 < K; k0 += 32) {
    #pragma unroll
    for (int i = 0; i < 2; ++i) {
      int row = w * 32 + i * 16;
      gld16(Arow + (size_t)(row + srow) * K + k0 + scol, As + row * 32);
    }
    gld16(Brow + (size_t)(w * 16 + srow) * K + k0 + scol, Bs + (w * 16) * 32);
    __syncthreads();
    short8 bf[2];
    #pragma unroll
    for (int ni = 0; ni < 2; ++ni)
      bf[ni] = *(const short8*)(Bs + (wn * 32 + ni * 16 + l15) * 32 + quad * 8);
    #pragma unroll
    for (int mi = 0; mi < 4; ++mi) {
      short8 af = *(const short8*)(As + (wm * 64 + mi * 16 + l15) * 32 + quad * 8);
      #pragma unroll
      for (int ni = 0; ni < 2; ++ni)
        acc[mi][ni] = __builtin_amdgcn_mfma_f32_16x16x32_bf16(af, bf[ni], acc[mi][ni], 0, 0, 0);
    }
    __syncthreads();
  }

  #pragma unroll
  for (int mi = 0; mi < 4; ++mi)
    #pragma unroll
    for (int ni = 0; ni < 2; ++ni) {
      const int n = blockN + wn * 32 + ni * 16 + l15;
      const float bv = bias[n];
      #pragma unroll
      for (int r = 0; r < 4; ++r) {
        const int m = blockM + wm * 64 + mi * 16 + quad * 4 + r;
        out[(size_t)m * N + n] = acc[mi][ni][r] + bv;
      }
    }
}

// ---------------- flash attention (S^T operand swap, P in registers) ----------------
// Q,K: bf16 [BH][S][64]; Vt: bf16 [BH][64][S]; ctx: bf16 [B][S][1024]
// QK: sc = mfma_16x16x32(A=K_frag, B=Q_frag) -> D[m=key][n=q]: lane holds q=l15,
// keys=kt*16+quad*4+r. That IS the A-layout of mfma_16x16x16bf16_1k (m=l15, k=quad*4+j),
// so exp2+pack happens in registers and feeds PV directly. l via ones-B MFMA.

__global__ __launch_bounds__(256) void attn_kernel(
    const unsigned short* __restrict__ Q, const unsigned short* __restrict__ Kg,
    const unsigned short* __restrict__ Vt, const float* __restrict__ maskAdd,
    unsigned short* __restrict__ ctx) {
  const int S = 2048;
  const int tid = threadIdx.x;
  const int w = tid >> 6, lane = tid & 63, quad = lane >> 4, l15 = lane & 15;
  const int qb = blockIdx.x, bh = blockIdx.y;
  const int b = bh >> 4, h = bh & 15;
  const int q0 = qb * 128;

  __shared__ unsigned short Ks[128 * 64];   // [key][e], XOR chunk-swizzled (8 chunks/row)
  __shared__ unsigned short Vs[64 * 128];   // [e][key], XOR chunk-swizzled (16 chunks/row)

  const unsigned short* Qb = Q + (size_t)bh * S * 64;
  const unsigned short* Kb = Kg + (size_t)bh * S * 64;
  const unsigned short* Vb = Vt + (size_t)bh * 64 * S;
  const float* mb = maskAdd + (size_t)b * S;

  // Q fragments (B-operand now; same register contents as A), pre-scaled 0.125*log2e
  const float qs = 0.125f * LOG2E;
  short8 qf[2][2];
  #pragma unroll
  for (int mi = 0; mi < 2; ++mi)
    #pragma unroll
    for (int kq = 0; kq < 2; ++kq) {
      short8 v = *(const short8*)(Qb + (size_t)(q0 + w * 32 + mi * 16 + l15) * 64 + kq * 32 + quad * 8);
      #pragma unroll
      for (int j = 0; j < 8; ++j)
        v[j] = (short)f32_bf16(bf16_f32((unsigned short)v[j]) * qs);
      qf[mi][kq] = v;
    }

  short4b ones4;
  #pragma unroll
  for (int j = 0; j < 4; ++j) ones4[j] = (short)0x3F80;  // bf16 1.0

  floatx4 O[2][4], ls[2];
  #pragma unroll
  for (int mi = 0; mi < 2; ++mi) {
    #pragma unroll
    for (int ne = 0; ne < 4; ++ne) O[mi][ne] = (floatx4){0.f, 0.f, 0.f, 0.f};
    ls[mi] = (floatx4){0.f, 0.f, 0.f, 0.f};
  }

  for (int t = 0; t < 16; ++t) {
    const int kv0 = t * 128;
    __syncthreads();  // prev tile fully consumed
    #pragma unroll
    for (int i = 0; i < 4; ++i) {  // K tile: 8 rows/issue, swizzled source
      int r0 = w * 32 + i * 8;
      int row = r0 + (lane >> 3);
      int cg = (lane & 7) ^ (row & 7);
      gld16(Kb + (size_t)(kv0 + row) * 64 + cg * 8, Ks + r0 * 64);
    }
    #pragma unroll
    for (int i = 0; i < 4; ++i) {  // V tile: 4 rows/issue, swizzled source
      int r0 = w * 16 + i * 4;
      int row = r0 + (lane >> 4);
      int p = lane & 15;
      int cg = (p & 8) | ((p & 7) ^ (row & 7));
      gld16(Vb + (size_t)row * S + kv0 + cg * 8, Vs + r0 * 128);
    }
    __syncthreads();  // staging visible

    #pragma unroll
    for (int ph = 0; ph < 2; ++ph) {
      // S^T scores: D[m=key][n=q], 64 keys x 32 q per wave per phase
      floatx4 sc[2][4];
      #pragma unroll
      for (int ni = 0; ni < 4; ++ni) {
        const int kt = ph * 4 + ni;
        const int krow = kt * 16 + l15;
        short8 kf0 = *(const short8*)(Ks + krow * 64 + ((quad) ^ (l15 & 7)) * 8);
        short8 kf1 = *(const short8*)(Ks + krow * 64 + ((4 + quad) ^ (l15 & 7)) * 8);
        #pragma unroll
        for (int mi = 0; mi < 2; ++mi) {
          floatx4 s = (floatx4){0.f, 0.f, 0.f, 0.f};
          s = __builtin_amdgcn_mfma_f32_16x16x32_bf16(kf0, qf[mi][0], s, 0, 0, 0);
          s = __builtin_amdgcn_mfma_f32_16x16x32_bf16(kf1, qf[mi][1], s, 0, 0, 0);
          sc[mi][ni] = s;
        }
      }
      // exp2 + pack (registers only), then PV + row-sum
      #pragma unroll
      for (int ni = 0; ni < 4; ++ni) {
        const int kt = ph * 4 + ni;
        const float4 mav = *(const float4*)(mb + kv0 + kt * 16 + quad * 4);
        short4b pf[2];
        #pragma unroll
        for (int mi = 0; mi < 2; ++mi) {
          float p0 = __builtin_amdgcn_exp2f(sc[mi][ni][0] + mav.x);
          float p1 = __builtin_amdgcn_exp2f(sc[mi][ni][1] + mav.y);
          float p2 = __builtin_amdgcn_exp2f(sc[mi][ni][2] + mav.z);
          float p3 = __builtin_amdgcn_exp2f(sc[mi][ni][3] + mav.w);
          pf[mi] = pack_bf16x4(p0, p1, p2, p3);
        }
        const int c = kt * 2 + (quad >> 1);
        const int pc = (c & 8) | ((c & 7) ^ (l15 & 7));
        #pragma unroll
        for (int ne = 0; ne < 4; ++ne) {
          short4b vf = *(const short4b*)(Vs + (ne * 16 + l15) * 128 + pc * 8 + (quad & 1) * 4);
          #pragma unroll
          for (int mi = 0; mi < 2; ++mi)
            O[mi][ne] = __builtin_amdgcn_mfma_f32_16x16x16bf16_1k(pf[mi], vf, O[mi][ne], 0, 0, 0);
        }
        #pragma unroll
        for (int mi = 0; mi < 2; ++mi)
          ls[mi] = __builtin_amdgcn_mfma_f32_16x16x16bf16_1k(pf[mi], ones4, ls[mi], 0, 0, 0);
      }
    }
  }

  // epilogue: ctx[b][s][h*64+e] = O / l   (O: col=e=l15 within ne-tile, row=q=quad*4+r)
  #pragma unroll
  for (int mi = 0; mi < 2; ++mi)
    #pragma unroll
    for (int r = 0; r < 4; ++r) {
      const float inv = __builtin_amdgcn_rcpf(ls[mi][r]);
      const int s = q0 + w * 32 + mi * 16 + quad * 4 + r;
      #pragma unroll
      for (int ne = 0; ne < 4; ++ne)
        ctx[((size_t)b * S + s) * 1024 + h * 64 + ne * 16 + l15] = f32_bf16(O[mi][ne][r] * inv);
    }
}

// ---------------- host ----------------

extern "C" void kernel_launch(void* const* d_in, const int* in_sizes, int n_in,
                              void* d_out, int out_size, void* d_ws, size_t ws_size,
                              hipStream_t stream) {
  const float* query = (const float*)d_in[0];
  const float* key   = (const float*)d_in[1];
  const float* value = (const float*)d_in[2];
  const int*   mask  = (const int*)d_in[3];
  const float* Wq = (const float*)d_in[4];
  const float* bq = (const float*)d_in[5];
  const float* Wk = (const float*)d_in[6];
  const float* bk = (const float*)d_in[7];
  const float* Wv = (const float*)d_in[8];
  const float* bv = (const float*)d_in[9];
  const float* Wo = (const float*)d_in[10];
  const float* bo = (const float*)d_in[11];
  float* out = (float*)d_out;

  char* ws = (char*)d_ws;
  const size_t MB = 1024 * 1024;
  unsigned short* qin  = (unsigned short*)(ws + 0);        // 8MB
  unsigned short* kin  = (unsigned short*)(ws + 8 * MB);   // 8MB
  unsigned short* vin  = (unsigned short*)(ws + 16 * MB);  // 8MB
  unsigned short* WqT  = (unsigned short*)(ws + 24 * MB);  // 2MB
  unsigned short* WkT  = (unsigned short*)(ws + 26 * MB);
  unsigned short* WvT  = (unsigned short*)(ws + 28 * MB);
  unsigned short* WoT  = (unsigned short*)(ws + 30 * MB);
  unsigned short* Qp   = (unsigned short*)(ws + 32 * MB);  // 8MB [BH][S][64]
  unsigned short* Kp   = (unsigned short*)(ws + 40 * MB);
  unsigned short* Vp   = (unsigned short*)(ws + 48 * MB);
  float* maskAdd       = (float*)(ws + 56 * MB);           // 16KB
  unsigned short* ctxb = qin;  // alias: qin consumed before attn writes ctx
  unsigned short* Vtb  = kin;  // alias: kin consumed before transpose_v writes Vt

  cvt3_kernel<<<dim3(4096, 3), 256, 0, stream>>>(query, key, value, qin, kin, vin,
                                                 mask, maskAdd, 1048576);
  transpose_w_kernel<<<dim3(32, 32, 49), 256, 0, stream>>>(Wq, Wk, Wv, Wo, WqT, WkT, WvT, WoT);

  ProjArgs pa;
  pa.A[0] = qin; pa.A[1] = kin; pa.A[2] = vin;
  pa.Bt[0] = WqT; pa.Bt[1] = WkT; pa.Bt[2] = WvT;
  pa.bias[0] = bq; pa.bias[1] = bk; pa.bias[2] = bv;
  pa.out[0] = Qp; pa.out[1] = Kp; pa.out[2] = Vp;
  gemm_proj_kernel<<<dim3(8, 32, 3), 256, 0, stream>>>(pa, 1024);

  transpose_v_kernel<<<dim3(64, 2, 32), 256, 0, stream>>>(Vp, Vtb, 2048, 64);
  attn_kernel<<<dim3(16, 32), 256, 0, stream>>>(Qp, Kp, Vtb, maskAdd, ctxb);
  gemm_out_kernel<<<dim3(16, 32), 256, 0, stream>>>(ctxb, WoT, bo, out, 1024, 1024);
}

// Round 4
// 257.739 us; speedup vs baseline: 1.0560x; 1.0560x over previous
//
#include <hip/hip_runtime.h>
#include <stdint.h>
#include <math.h>

// MultiHeadAttention: B=2, S=2048, D=1024, H=16, DH=64
// R4: attn reverted to R2 version (16x16x32 PV via LDS P round-trip — R3's
// 16x16x16 operand-swap halved MFMA rate). transpose_v deleted: proj z=2 runs
// transposed (A=WvT M-side, vin N-side) writing Vt [BH][64][S] directly.

typedef __attribute__((ext_vector_type(8))) short short8;
typedef __attribute__((ext_vector_type(4))) float floatx4;

#define LOG2E 1.44269504088896340736f

__device__ __forceinline__ unsigned short f32_bf16(float f) {
  union { float f; unsigned u; } c; c.f = f;
  return (unsigned short)((c.u + 0x7FFFu + ((c.u >> 16) & 1u)) >> 16);
}
__device__ __forceinline__ float bf16_f32(unsigned short u) {
  union { unsigned u; float f; } c; c.u = ((unsigned)u) << 16;
  return c.f;
}
__device__ __forceinline__ void gld16(const void* g, void* l) {
  __builtin_amdgcn_global_load_lds((const __attribute__((address_space(1))) void*)g,
                                   (__attribute__((address_space(3))) void*)l, 16, 0, 0);
}

// ---------------- pre-passes ----------------

__global__ __launch_bounds__(256) void cvt3_kernel(
    const float* __restrict__ a, const float* __restrict__ b, const float* __restrict__ c,
    unsigned short* __restrict__ oa, unsigned short* __restrict__ ob, unsigned short* __restrict__ oc,
    const int* __restrict__ mask, float* __restrict__ mb, int n4) {
  int i = blockIdx.x * 256 + threadIdx.x;
  if (blockIdx.y == 0 && blockIdx.x < 16) {  // fused mask bias (4096 elems)
    int j = blockIdx.x * 256 + threadIdx.x;
    mb[j] = (mask[j] == 0) ? (-1.0e9f * LOG2E) : 0.0f;
  }
  if (i >= n4) return;
  const float* in; unsigned short* out;
  if (blockIdx.y == 0) { in = a; out = oa; }
  else if (blockIdx.y == 1) { in = b; out = ob; }
  else { in = c; out = oc; }
  float4 v = reinterpret_cast<const float4*>(in)[i];
  ushort4 o;
  o.x = f32_bf16(v.x); o.y = f32_bf16(v.y); o.z = f32_bf16(v.z); o.w = f32_bf16(v.w);
  reinterpret_cast<ushort4*>(out)[i] = o;
}

// merged weight transposes: z<48 -> per-head qkv [16][1024][64]; z==48 -> Wo [1024][1024]
__global__ __launch_bounds__(256) void transpose_w_kernel(
    const float* __restrict__ w0, const float* __restrict__ w1, const float* __restrict__ w2,
    const float* __restrict__ wo,
    unsigned short* __restrict__ o0, unsigned short* __restrict__ o1, unsigned short* __restrict__ o2,
    unsigned short* __restrict__ oo) {
  __shared__ float t[32][33];
  const int tx = threadIdx.x & 31, ty = threadIdx.x >> 5;
  const int zb = blockIdx.z;
  const float* in; unsigned short* out; int R, C, z, r0, c0;
  if (zb < 48) {
    if (blockIdx.y >= 2) return;
    const int sel = zb >> 4; z = zb & 15;
    in = (sel == 0) ? w0 : (sel == 1) ? w1 : w2;
    out = (sel == 0) ? o0 : (sel == 1) ? o1 : o2;
    R = 1024; C = 64;
  } else {
    in = wo; out = oo; R = 1024; C = 1024; z = 0;
  }
  r0 = blockIdx.x * 32; c0 = blockIdx.y * 32;
  const float* inp = in + (size_t)z * R * C;
  #pragma unroll
  for (int j = 0; j < 4; ++j)
    t[ty + j * 8][tx] = inp[(size_t)(r0 + ty + j * 8) * C + c0 + tx];
  __syncthreads();
  #pragma unroll
  for (int j = 0; j < 4; ++j)
    out[((size_t)z * C + c0 + ty + j * 8) * R + r0 + tx] = f32_bf16(t[tx][ty + j * 8]);
}

// ---------------- GEMM core 128x128 (m97 structure) ----------------

__device__ __forceinline__ void gemm_core(
    const unsigned short* __restrict__ A, const unsigned short* __restrict__ Bt,
    int K, int blockM, int blockN,
    unsigned short* As, unsigned short* Bs, floatx4 acc[4][4]) {
  const int tid = threadIdx.x;
  const int w = tid >> 6;
  const int lane = tid & 63;
  const int quad = lane >> 4, l15 = lane & 15;
  const int wm = w & 1, wn = w >> 1;
  const int srow = lane >> 2;
  const int scol = (lane & 3) * 8;

  #pragma unroll
  for (int mi = 0; mi < 4; ++mi)
    #pragma unroll
    for (int ni = 0; ni < 4; ++ni)
      acc[mi][ni] = (floatx4){0.f, 0.f, 0.f, 0.f};

  const unsigned short* Arow = A + (size_t)blockM * K;
  const unsigned short* Brow = Bt + (size_t)blockN * K;

  for (int k0 = 0; k0 < K; k0 += 32) {
    #pragma unroll
    for (int i = 0; i < 2; ++i) {
      int row = w * 32 + i * 16;
      gld16(Arow + (size_t)(row + srow) * K + k0 + scol, As + row * 32);
      gld16(Brow + (size_t)(row + srow) * K + k0 + scol, Bs + row * 32);
    }
    __syncthreads();
    short8 bf[4];
    #pragma unroll
    for (int ni = 0; ni < 4; ++ni)
      bf[ni] = *(const short8*)(Bs + (wn * 64 + ni * 16 + l15) * 32 + quad * 8);
    #pragma unroll
    for (int mi = 0; mi < 4; ++mi) {
      short8 af = *(const short8*)(As + (wm * 64 + mi * 16 + l15) * 32 + quad * 8);
      #pragma unroll
      for (int ni = 0; ni < 4; ++ni)
        acc[mi][ni] = __builtin_amdgcn_mfma_f32_16x16x32_bf16(af, bf[ni], acc[mi][ni], 0, 0, 0);
    }
    __syncthreads();
  }
}

// projections. z=0/1: Q/K -> [BH][S][64]. z=2: transposed orientation, V^T -> [BH][64][S].
__global__ __launch_bounds__(256) void gemm_proj_kernel(
    const unsigned short* __restrict__ qin, const unsigned short* __restrict__ kin,
    const unsigned short* __restrict__ vin,
    const unsigned short* __restrict__ WqT, const unsigned short* __restrict__ WkT,
    const unsigned short* __restrict__ WvT,
    const float* __restrict__ bq, const float* __restrict__ bk, const float* __restrict__ bv,
    unsigned short* __restrict__ Qp, unsigned short* __restrict__ Kp,
    unsigned short* __restrict__ Vt) {
  __shared__ unsigned short As[128 * 32];
  __shared__ unsigned short Bs[128 * 32];
  const int z = blockIdx.y, bx = blockIdx.x;
  const unsigned short *A, *Bt;
  const float* bias;
  int blockM, blockN;
  if (z < 2) {
    blockN = (bx & 7) * 128; blockM = (bx >> 3) * 128;
    A = z ? kin : qin; Bt = z ? WkT : WqT; bias = z ? bk : bq;
  } else {
    blockM = (bx & 7) * 128; blockN = (bx >> 3) * 128;
    A = WvT; Bt = vin; bias = bv;
  }
  floatx4 acc[4][4];
  gemm_core(A, Bt, 1024, blockM, blockN, As, Bs, acc);

  const int tid = threadIdx.x, w = tid >> 6, lane = tid & 63;
  const int quad = lane >> 4, l15 = lane & 15;
  const int wm = w & 1, wn = w >> 1;

  if (z < 2) {
    unsigned short* outp = z ? Kp : Qp;
    #pragma unroll
    for (int mi = 0; mi < 4; ++mi)
      #pragma unroll
      for (int ni = 0; ni < 4; ++ni) {
        const int n = blockN + wn * 64 + ni * 16 + l15;
        const int h = n >> 6, e = n & 63;
        const float bvv = bias[n];
        #pragma unroll
        for (int r = 0; r < 4; ++r) {
          const int m = blockM + wm * 64 + mi * 16 + quad * 4 + r;
          const int b = m >> 11, s = m & 2047;
          outp[(((size_t)b * 16 + h) * 2048 + s) * 64 + e] = f32_bf16(acc[mi][ni][r] + bvv);
        }
      }
  } else {
    #pragma unroll
    for (int mi = 0; mi < 4; ++mi) {
      float br[4];
      #pragma unroll
      for (int r = 0; r < 4; ++r)
        br[r] = bias[blockM + wm * 64 + mi * 16 + quad * 4 + r];
      #pragma unroll
      for (int ni = 0; ni < 4; ++ni) {
        const int n = blockN + wn * 64 + ni * 16 + l15;   // global s-index
        const int b = n >> 11, s = n & 2047;
        #pragma unroll
        for (int r = 0; r < 4; ++r) {
          const int m = blockM + wm * 64 + mi * 16 + quad * 4 + r;  // global e-index
          const int h = m >> 6, e = m & 63;
          Vt[(((size_t)b * 16 + h) * 64 + e) * 2048 + s] = f32_bf16(acc[mi][ni][r] + br[r]);
        }
      }
    }
  }
}

// output projection, tile 128M x 64N -> 512 blocks (2/CU)
__global__ __launch_bounds__(256) void gemm_out_kernel(
    const unsigned short* __restrict__ A, const unsigned short* __restrict__ Bt,
    const float* __restrict__ bias, float* __restrict__ out, int K, int N) {
  __shared__ unsigned short As[128 * 32];
  __shared__ unsigned short Bs[64 * 32];
  const int tid = threadIdx.x;
  const int w = tid >> 6, lane = tid & 63;
  const int quad = lane >> 4, l15 = lane & 15;
  const int wm = w & 1, wn = w >> 1;
  const int srow = lane >> 2;
  const int scol = (lane & 3) * 8;
  const int blockN = blockIdx.x * 64, blockM = blockIdx.y * 128;

  floatx4 acc[4][2];
  #pragma unroll
  for (int mi = 0; mi < 4; ++mi)
    #pragma unroll
    for (int ni = 0; ni < 2; ++ni)
      acc[mi][ni] = (floatx4){0.f, 0.f, 0.f, 0.f};

  const unsigned short* Arow = A + (size_t)blockM * K;
  const unsigned short* Brow = Bt + (size_t)blockN * K;

  for (int k0 = 0; k0 < K; k0 += 32) {
    #pragma unroll
    for (int i = 0; i < 2; ++i) {
      int row = w * 32 + i * 16;
      gld16(Arow + (size_t)(row + srow) * K + k0 + scol, As + row * 32);
    }
    gld16(Brow + (size_t)(w * 16 + srow) * K + k0 + scol, Bs + (w * 16) * 32);
    __syncthreads();
    short8 bf[2];
    #pragma unroll
    for (int ni = 0; ni < 2; ++ni)
      bf[ni] = *(const short8*)(Bs + (wn * 32 + ni * 16 + l15) * 32 + quad * 8);
    #pragma unroll
    for (int mi = 0; mi < 4; ++mi) {
      short8 af = *(const short8*)(As + (wm * 64 + mi * 16 + l15) * 32 + quad * 8);
      #pragma unroll
      for (int ni = 0; ni < 2; ++ni)
        acc[mi][ni] = __builtin_amdgcn_mfma_f32_16x16x32_bf16(af, bf[ni], acc[mi][ni], 0, 0, 0);
    }
    __syncthreads();
  }

  #pragma unroll
  for (int mi = 0; mi < 4; ++mi)
    #pragma unroll
    for (int ni = 0; ni < 2; ++ni) {
      const int n = blockN + wn * 32 + ni * 16 + l15;
      const float bv = bias[n];
      #pragma unroll
      for (int r = 0; r < 4; ++r) {
        const int m = blockM + wm * 64 + mi * 16 + quad * 4 + r;
        out[(size_t)m * N + n] = acc[mi][ni][r] + bv;
      }
    }
}

// ---------------- flash attention (R2 version — verified 70 us) ----------------
// Q,K: bf16 [BH][S][64]; Vt: bf16 [BH][64][S]; ctx: bf16 [B][S][1024]
// XOR chunk swizzle on all LDS tiles: phys_chunk = (c&8) | ((c&7) ^ f(row)).
// No running max (scores bounded). l via ones-column MFMA.

__global__ __launch_bounds__(256, 3) void attn_kernel(
    const unsigned short* __restrict__ Q, const unsigned short* __restrict__ Kg,
    const unsigned short* __restrict__ Vt, const float* __restrict__ maskAdd,
    unsigned short* __restrict__ ctx) {
  const int S = 2048;
  const int tid = threadIdx.x;
  const int w = tid >> 6, lane = tid & 63, quad = lane >> 4, l15 = lane & 15;
  const int qb = blockIdx.x, bh = blockIdx.y;
  const int b = bh >> 4, h = bh & 15;
  const int q0 = qb * 128;

  __shared__ unsigned short Ks[128 * 64];   // [key][e], swizzled, 8 chunks/row
  __shared__ unsigned short Vs[64 * 128];   // [e][key], swizzled, 16 chunks/row
  __shared__ unsigned short Ps[4][32 * 64]; // per-wave, per-phase [q][key64], swizzled
  unsigned short* Pw = Ps[w];

  const unsigned short* Qb = Q + (size_t)bh * S * 64;
  const unsigned short* Kb = Kg + (size_t)bh * S * 64;
  const unsigned short* Vb = Vt + (size_t)bh * 64 * S;
  const float* mb = maskAdd + (size_t)b * S;

  // Q fragments, pre-scaled by 0.125 * log2(e)
  const float qs = 0.125f * LOG2E;
  short8 qf[2][2];
  #pragma unroll
  for (int mi = 0; mi < 2; ++mi)
    #pragma unroll
    for (int kq = 0; kq < 2; ++kq) {
      short8 v = *(const short8*)(Qb + (size_t)(q0 + w * 32 + mi * 16 + l15) * 64 + kq * 32 + quad * 8);
      #pragma unroll
      for (int j = 0; j < 8; ++j)
        v[j] = (short)f32_bf16(bf16_f32((unsigned short)v[j]) * qs);
      qf[mi][kq] = v;
    }

  short8 onesf;
  #pragma unroll
  for (int j = 0; j < 8; ++j) onesf[j] = (short)0x3F80;  // bf16 1.0

  floatx4 O[2][4], ls[2];
  #pragma unroll
  for (int mi = 0; mi < 2; ++mi) {
    #pragma unroll
    for (int ne = 0; ne < 4; ++ne) O[mi][ne] = (floatx4){0.f, 0.f, 0.f, 0.f};
    ls[mi] = (floatx4){0.f, 0.f, 0.f, 0.f};
  }

  for (int t = 0; t < 16; ++t) {
    const int kv0 = t * 128;
    __syncthreads();  // prev tile fully consumed
    #pragma unroll
    for (int i = 0; i < 4; ++i) {  // K tile staging, swizzled source chunks
      int r0 = w * 32 + i * 8;
      int row = r0 + (lane >> 3);
      int cg = (lane & 7) ^ (row & 7);
      gld16(Kb + (size_t)(kv0 + row) * 64 + cg * 8, Ks + r0 * 64);
    }
    #pragma unroll
    for (int i = 0; i < 4; ++i) {  // V tile staging
      int r0 = w * 16 + i * 4;
      int row = r0 + (lane >> 4);
      int p = lane & 15;
      int cg = (p & 8) | ((p & 7) ^ (row & 7));
      gld16(Vb + (size_t)row * S + kv0 + cg * 8, Vs + r0 * 128);
    }
    float ma[8];
    #pragma unroll
    for (int ni = 0; ni < 8; ++ni) ma[ni] = mb[kv0 + ni * 16 + l15];
    __syncthreads();  // staging visible

    #pragma unroll
    for (int ph = 0; ph < 2; ++ph) {
      floatx4 sc[2][4];
      #pragma unroll
      for (int ni = 0; ni < 4; ++ni) {
        const int key = (ph * 4 + ni) * 16 + l15;
        short8 kf0 = *(const short8*)(Ks + key * 64 + ((quad) ^ (l15 & 7)) * 8);
        short8 kf1 = *(const short8*)(Ks + key * 64 + ((4 + quad) ^ (l15 & 7)) * 8);
        #pragma unroll
        for (int mi = 0; mi < 2; ++mi) {
          floatx4 s = (floatx4){0.f, 0.f, 0.f, 0.f};
          s = __builtin_amdgcn_mfma_f32_16x16x32_bf16(qf[mi][0], kf0, s, 0, 0, 0);
          s = __builtin_amdgcn_mfma_f32_16x16x32_bf16(qf[mi][1], kf1, s, 0, 0, 0);
          sc[mi][ni] = s;
        }
      }
      // p = exp2(sc + mask), bf16-truncated into swizzled Pw
      #pragma unroll
      for (int mi = 0; mi < 2; ++mi)
        #pragma unroll
        for (int r = 0; r < 4; ++r) {
          const int row = mi * 16 + quad * 4 + r;
          const int g = (row + (row >> 3)) & 7;
          #pragma unroll
          for (int ni = 0; ni < 4; ++ni) {
            float p = __builtin_amdgcn_exp2f(sc[mi][ni][r] + ma[ph * 4 + ni]);
            union { float f; unsigned u; } c; c.f = p;
            const int ch = (ni * 2 + (l15 >> 3)) ^ g;
            Pw[row * 64 + (ch & 7) * 8 + (l15 & 7)] = (unsigned short)(c.u >> 16);
          }
        }
      // PV + row-sum
      #pragma unroll
      for (int kkl = 0; kkl < 2; ++kkl) {
        const int kk = ph * 2 + kkl;
        short8 pfr[2], vf[4];
        #pragma unroll
        for (int mi = 0; mi < 2; ++mi) {
          const int gp = (2 * mi + l15 + (l15 >> 3)) & 7;
          pfr[mi] = *(const short8*)(Pw + (mi * 16 + l15) * 64 + ((kkl * 4 + quad) ^ gp) * 8);
        }
        #pragma unroll
        for (int ne = 0; ne < 4; ++ne) {
          const int c = kk * 4 + quad;
          vf[ne] = *(const short8*)(Vs + (ne * 16 + l15) * 128 + ((c & 8) | ((c & 7) ^ (l15 & 7))) * 8);
        }
        #pragma unroll
        for (int mi = 0; mi < 2; ++mi) {
          #pragma unroll
          for (int ne = 0; ne < 4; ++ne)
            O[mi][ne] = __builtin_amdgcn_mfma_f32_16x16x32_bf16(pfr[mi], vf[ne], O[mi][ne], 0, 0, 0);
          ls[mi] = __builtin_amdgcn_mfma_f32_16x16x32_bf16(pfr[mi], onesf, ls[mi], 0, 0, 0);
        }
      }
    }
  }

  // epilogue: ctx[b][s][h*64+e] = O / l
  #pragma unroll
  for (int mi = 0; mi < 2; ++mi)
    #pragma unroll
    for (int r = 0; r < 4; ++r) {
      const float inv = __builtin_amdgcn_rcpf(ls[mi][r]);
      const int s = q0 + w * 32 + mi * 16 + quad * 4 + r;
      #pragma unroll
      for (int ne = 0; ne < 4; ++ne)
        ctx[((size_t)b * S + s) * 1024 + h * 64 + ne * 16 + l15] = f32_bf16(O[mi][ne][r] * inv);
    }
}

// ---------------- host ----------------

extern "C" void kernel_launch(void* const* d_in, const int* in_sizes, int n_in,
                              void* d_out, int out_size, void* d_ws, size_t ws_size,
                              hipStream_t stream) {
  const float* query = (const float*)d_in[0];
  const float* key   = (const float*)d_in[1];
  const float* value = (const float*)d_in[2];
  const int*   mask  = (const int*)d_in[3];
  const float* Wq = (const float*)d_in[4];
  const float* bq = (const float*)d_in[5];
  const float* Wk = (const float*)d_in[6];
  const float* bk = (const float*)d_in[7];
  const float* Wv = (const float*)d_in[8];
  const float* bv = (const float*)d_in[9];
  const float* Wo = (const float*)d_in[10];
  const float* bo = (const float*)d_in[11];
  float* out = (float*)d_out;

  char* ws = (char*)d_ws;
  const size_t MB = 1024 * 1024;
  unsigned short* qin  = (unsigned short*)(ws + 0);        // 8MB
  unsigned short* kin  = (unsigned short*)(ws + 8 * MB);   // 8MB
  unsigned short* vin  = (unsigned short*)(ws + 16 * MB);  // 8MB
  unsigned short* WqT  = (unsigned short*)(ws + 24 * MB);  // 2MB
  unsigned short* WkT  = (unsigned short*)(ws + 26 * MB);
  unsigned short* WvT  = (unsigned short*)(ws + 28 * MB);
  unsigned short* WoT  = (unsigned short*)(ws + 30 * MB);
  unsigned short* Qp   = (unsigned short*)(ws + 32 * MB);  // 8MB [BH][S][64]
  unsigned short* Kp   = (unsigned short*)(ws + 40 * MB);  // 8MB [BH][S][64]
  unsigned short* Vt   = (unsigned short*)(ws + 48 * MB);  // 8MB [BH][64][S]
  float* maskAdd       = (float*)(ws + 56 * MB);           // 16KB
  unsigned short* ctxb = qin;  // alias: qin consumed by proj before attn writes ctx

  cvt3_kernel<<<dim3(4096, 3), 256, 0, stream>>>(query, key, value, qin, kin, vin,
                                                 mask, maskAdd, 1048576);
  transpose_w_kernel<<<dim3(32, 32, 49), 256, 0, stream>>>(Wq, Wk, Wv, Wo, WqT, WkT, WvT, WoT);
  gemm_proj_kernel<<<dim3(256, 3), 256, 0, stream>>>(qin, kin, vin, WqT, WkT, WvT,
                                                     bq, bk, bv, Qp, Kp, Vt);
  attn_kernel<<<dim3(16, 32), 256, 0, stream>>>(Qp, Kp, Vt, maskAdd, ctxb);
  gemm_out_kernel<<<dim3(16, 32), 256, 0, stream>>>(ctxb, WoT, bo, out, 1024, 1024);
}